// Round 1
// baseline (584.316 us; speedup 1.0000x reference)
//
#include <hip/hip_runtime.h>

// NNLS via normal equations + FISTA, matching the JAX reference.
// Phase 1 (memory-bound): M = U^T U for U = [X | y | 1]  (2e6 x 37), padded to 40.
// Phase 2 (serial):       power iteration (50) + FISTA (400) on the 33x33 system,
//                         one wave per output column.

#define NROWS 2000000
#define TR 64               // tile rows per block iteration
#define NT (NROWS / TR)     // 31250 tiles, exact
#define US 40               // padded row stride in floats (16B-aligned rows)
#define GRAM_BLOCKS 2048
#define PITERS 50
#define QPITERS 400

__device__ __forceinline__ float lane_bcast(float x, int l) {
  return __int_as_float(__builtin_amdgcn_readlane(__float_as_int(x), l));
}

__global__ __launch_bounds__(256) void zero_kernel(float* __restrict__ Mw) {
  int i = blockIdx.x * 256 + threadIdx.x;
  if (i < 1600) Mw[i] = 0.f;
}

// u-row layout: [x0..x31 | y0..y3 | 1 | 0 0 0]   (indices 0..31, 32..35, 36, 37..39)
__global__ __launch_bounds__(256) void gram_kernel(const float* __restrict__ X,
                                                   const float* __restrict__ Yg,
                                                   float* __restrict__ Mw) {
  __shared__ float sm[3520];  // union: tile u[64][40] (2560 floats) / reduction (3520 floats)
  const int tid  = threadIdx.x;
  const int lane = tid & 63;
  const int wv   = tid >> 6;

  // decode lane -> upper-triangle 4x4 block (bi <= bj) of the 10x10 block grid
  int ll = (lane < 55) ? lane : 0;
  int bi = 0, rem = ll;
  { int t2 = 10; while (rem >= t2) { rem -= t2; --t2; ++bi; } }
  const int bj = bi + rem;
  const int bi4 = bi * 4, bj4 = bj * 4;

  const int r0 = tid >> 3;   // 0..31 (this thread stages rows r0 and r0+32)
  const int ch = tid & 7;    // float4 chunk within the 32-float x row
  const float4* X4 = (const float4*)X;
  const float4* Y4 = (const float4*)Yg;

  float acc[4][4];
#pragma unroll
  for (int p = 0; p < 4; ++p)
#pragma unroll
    for (int q = 0; q < 4; ++q) acc[p][q] = 0.f;

  for (int tile = blockIdx.x; tile < NT; tile += GRAM_BLOCKS) {
    const int gr = tile * TR;
    // issue global loads early (overlap previous tile's compute)
    float4 v0 = X4[(size_t)(gr + r0) * 8 + ch];
    float4 v1 = X4[(size_t)(gr + r0 + 32) * 8 + ch];
    float4 yv = make_float4(0.f, 0.f, 0.f, 0.f);
    if (tid < TR) yv = Y4[gr + tid];

    __syncthreads();  // previous compute done -> LDS free
    *(float4*)&sm[r0 * US + ch * 4]        = v0;
    *(float4*)&sm[(r0 + 32) * US + ch * 4] = v1;
    if (tid < TR) {
      *(float4*)&sm[tid * US + 32] = yv;
      *(float4*)&sm[tid * US + 36] = make_float4(1.f, 0.f, 0.f, 0.f);  // ones col + zero pad
    }
    __syncthreads();

    const int rbase = wv * 16;  // each wave handles 16 of the 64 rows
#pragma unroll 4
    for (int rr = 0; rr < 16; ++rr) {
      const float* rowp = &sm[(rbase + rr) * US];
      float4 a = *(const float4*)&rowp[bi4];
      float4 b = *(const float4*)&rowp[bj4];
      float av[4] = {a.x, a.y, a.z, a.w};
      float bv[4] = {b.x, b.y, b.z, b.w};
#pragma unroll
      for (int p = 0; p < 4; ++p)
#pragma unroll
        for (int q = 0; q < 4; ++q) acc[p][q] = fmaf(av[p], bv[q], acc[p][q]);
    }
  }

  // block-level reduction across the 4 waves, then one atomicAdd per entry
  __syncthreads();
  if (lane < 55) {
#pragma unroll
    for (int p = 0; p < 4; ++p)
#pragma unroll
      for (int q = 0; q < 4; ++q)
        sm[wv * 880 + lane * 16 + p * 4 + q] = acc[p][q];
  }
  __syncthreads();
  for (int e = tid; e < 880; e += 256) {
    float s = sm[e] + sm[e + 880] + sm[e + 1760] + sm[e + 2640];
    int l2 = e >> 4, pq = e & 15;
    int b1 = 0, r2 = l2;
    { int t2 = 10; while (r2 >= t2) { r2 -= t2; --t2; ++b1; } }
    int b2 = b1 + r2;
    int gi = b1 * 4 + (pq >> 2), gj = b2 * 4 + (pq & 3);
    atomicAdd(&Mw[gi * 40 + gj], s);  // pads hold exact zeros, harmless
  }
}

// A-col index a in [0,33): u-index U(a) = a<32 ? a : 36 (ones col). c cols = u 32..35.
__global__ __launch_bounds__(256) void solve_kernel(const float* __restrict__ Mw,
                                                    float* __restrict__ out) {
  const int tid  = threadIdx.x;
  const int lane = tid & 63;
  const int col  = tid >> 6;         // one wave per output column (independent QPs)
  const bool act = lane < 33;
  const int i  = act ? lane : 0;
  const int Ui = (i < 32) ? i : 36;

  // G row i in registers (only upper block-triangle of M is populated -> mirror)
  float Gr[33];
#pragma unroll
  for (int k = 0; k < 33; ++k) {
    const int Uk = (k < 32) ? k : 36;
    Gr[k] = ((Ui >> 2) <= (Uk >> 2)) ? Mw[Ui * 40 + Uk] : Mw[Uk * 40 + Ui];
  }
  const int cj = 32 + col;
  const float ci = ((Ui >> 2) <= (cj >> 2)) ? Mw[Ui * 40 + cj] : Mw[cj * 40 + Ui];

  // power iteration for L = lambda_max(G), replicated per wave (no sync needed)
  float v = rsqrtf(33.f);
  for (int it = 0; it < PITERS; ++it) {
    float w = 0.f;
#pragma unroll
    for (int k = 0; k < 33; ++k) w = fmaf(Gr[k], lane_bcast(v, k), w);
    float x = act ? w * w : 0.f;
#pragma unroll
    for (int off = 32; off; off >>= 1) x += __shfl_xor(x, off);
    v = w * rsqrtf(x);
  }
  float w = 0.f;
#pragma unroll
  for (int k = 0; k < 33; ++k) w = fmaf(Gr[k], lane_bcast(v, k), w);
  float x = act ? v * w : 0.f;
#pragma unroll
  for (int off = 32; off; off >>= 1) x += __shfl_xor(x, off);
  const float step = 1.f / x;

  // FISTA: Zn = proj(Y - step*(G@Y - c)); Yn = Zn + ((t-1)/tn)*(Zn - Z)
  float Z = 0.f, Y = 0.f, t = 1.f;
  for (int it = 0; it < QPITERS; ++it) {
    float g = 0.f;
#pragma unroll
    for (int k = 0; k < 33; ++k) g = fmaf(Gr[k], lane_bcast(Y, k), g);
    float zn = Y - step * (g - ci);
    if (i < 32) zn = fmaxf(zn, 0.f);   // W rows clamped; bias row (i==32) free
    float tn = 0.5f * (1.f + sqrtf(fmaf(4.f * t, t, 1.f)));
    float beta = (t - 1.f) / tn;
    float yn = fmaf(beta, zn - Z, zn);
    Z = zn; Y = yn; t = tn;
  }
  if (lane < 32) out[lane * 4 + col] = Z;  // W is [32,4] row-major
}

extern "C" void kernel_launch(void* const* d_in, const int* in_sizes, int n_in,
                              void* d_out, int out_size, void* d_ws, size_t ws_size,
                              hipStream_t stream) {
  const float* X  = (const float*)d_in[0];
  const float* Yg = (const float*)d_in[1];
  float* Mw  = (float*)d_ws;
  float* out = (float*)d_out;

  hipLaunchKernelGGL(zero_kernel, dim3(7), dim3(256), 0, stream, Mw);
  hipLaunchKernelGGL(gram_kernel, dim3(GRAM_BLOCKS), dim3(256), 0, stream, X, Yg, Mw);
  hipLaunchKernelGGL(solve_kernel, dim3(1), dim3(256), 0, stream, Mw, out);
}

// Round 2
// 542.885 us; speedup vs baseline: 1.0763x; 1.0763x over previous
//
#include <hip/hip_runtime.h>

// NNLS via normal equations + FISTA.
// Phase 1: M = U^T U, U = [X | y | 1] (2e6 x 37, padded to 40). 8x8 per-lane
//          patches, 4 teams/wave, software-prefetched tiles.
// Phase 2: power iteration (15) + FISTA (80) on the 33x33 system; Y broadcast
//          via double-buffered LDS (no readlane), one wave per output column.

#define NROWS 2000000
#define TR 64                 // tile rows
#define NT (NROWS / TR)       // 31250 tiles, exact
#define US 44                 // LDS row stride in floats (16B-aligned, 3-way max aliasing)
#define GRAM_BLOCKS 1024      // 4 blocks/CU, all co-resident
#define PITERS 15
#define QPITERS 80

__global__ __launch_bounds__(256) void zero_kernel(float* __restrict__ Mw) {
  int i = blockIdx.x * 256 + threadIdx.x;
  if (i < 1600) Mw[i] = 0.f;
}

// u-row layout: [x0..x31 | y0..y3 | 1 | 0 0 0] = cols 0..39 (40..43 unused pad)
__global__ __launch_bounds__(256, 4) void gram_kernel(const float* __restrict__ X,
                                                      const float* __restrict__ Yg,
                                                      float* __restrict__ Mw) {
  __shared__ float sm[3840];  // union: tile 64*44=2816 / reduction 4*960=3840
  const int tid  = threadIdx.x;
  const int lane = tid & 63;
  const int wv   = tid >> 6;
  const int team = lane >> 4;   // 4 teams of 16 lanes
  const int p    = lane & 15;   // patch id; 15 active (p<15)

  // patch p -> (PI,PJ), upper triangle of the 5x5 grid of 8x8 blocks
  int pp = (p < 15) ? p : 0;
  int PI = 0, rem = pp;
  while (rem >= 5 - PI) { rem -= 5 - PI; ++PI; }
  const int PJ = PI + rem;
  const int ca = PI * 8, cb = PJ * 8;

  const int r0 = tid >> 3;   // staging: row (and row+32)
  const int ch = tid & 7;    // float4 chunk within 32-float x row
  const float4* X4 = (const float4*)X;
  const float4* Y4 = (const float4*)Yg;

  float acc[8][8];
#pragma unroll
  for (int a = 0; a < 8; ++a)
#pragma unroll
    for (int b = 0; b < 8; ++b) acc[a][b] = 0.f;

  // prologue: load first tile into registers
  int tile = blockIdx.x;
  float4 v0, v1, yv;
  {
    const int gr = tile * TR;
    v0 = X4[(size_t)(gr + r0) * 8 + ch];
    v1 = X4[(size_t)(gr + r0 + 32) * 8 + ch];
    yv = (tid < TR) ? Y4[gr + tid] : make_float4(0.f, 0.f, 0.f, 0.f);
  }

  const int rbase = wv * 16 + team;  // team-spacing 1 within the wave's 16 rows

  while (tile < NT) {
    __syncthreads();  // previous compute done -> LDS reusable
    *(float4*)&sm[r0 * US + ch * 4]        = v0;
    *(float4*)&sm[(r0 + 32) * US + ch * 4] = v1;
    if (tid < TR) {
      *(float4*)&sm[tid * US + 32] = yv;
      *(float4*)&sm[tid * US + 36] = make_float4(1.f, 0.f, 0.f, 0.f);
    }
    __syncthreads();

    // prefetch next tile: latency hides under this tile's compute
    const int nt = tile + GRAM_BLOCKS;
    if (nt < NT) {
      const int gr = nt * TR;
      v0 = X4[(size_t)(gr + r0) * 8 + ch];
      v1 = X4[(size_t)(gr + r0 + 32) * 8 + ch];
      if (tid < TR) yv = Y4[gr + tid];
    }

#pragma unroll
    for (int rs = 0; rs < 4; ++rs) {
      const float* rowp = &sm[(rbase + rs * 4) * US];
      float4 a0 = *(const float4*)&rowp[ca];
      float4 a1 = *(const float4*)&rowp[ca + 4];
      float4 b0 = *(const float4*)&rowp[cb];
      float4 b1 = *(const float4*)&rowp[cb + 4];
      float av[8] = {a0.x, a0.y, a0.z, a0.w, a1.x, a1.y, a1.z, a1.w};
      float bv[8] = {b0.x, b0.y, b0.z, b0.w, b1.x, b1.y, b1.z, b1.w};
#pragma unroll
      for (int a = 0; a < 8; ++a)
#pragma unroll
        for (int b = 0; b < 8; ++b) acc[a][b] = fmaf(av[a], bv[b], acc[a][b]);
    }
    tile = nt;
  }

  // cross-team reduce (teams are lane bits 4,5)
#pragma unroll
  for (int a = 0; a < 8; ++a)
#pragma unroll
    for (int b = 0; b < 8; ++b) {
      float v = acc[a][b];
      v += __shfl_xor(v, 16);
      v += __shfl_xor(v, 32);
      acc[a][b] = v;
    }
  __syncthreads();
  if (p < 15 && team == 0) {
#pragma unroll
    for (int a = 0; a < 8; ++a)
#pragma unroll
      for (int b = 0; b < 8; ++b)
        sm[wv * 960 + p * 64 + a * 8 + b] = acc[a][b];
  }
  __syncthreads();
  for (int e = tid; e < 960; e += 256) {
    float s = sm[e] + sm[e + 960] + sm[e + 1920] + sm[e + 2880];
    int pe = e >> 6, idx = e & 63;
    int bi = 0, r2 = pe;
    while (r2 >= 5 - bi) { r2 -= 5 - bi; ++bi; }
    int bj = bi + r2;
    atomicAdd(&Mw[(bi * 8 + (idx >> 3)) * 40 + (bj * 8 + (idx & 7))], s);
  }
}

// dot of 36-float register row with 36-float LDS vector (uniform address = broadcast)
__device__ __forceinline__ float dot36(const float* __restrict__ Gr, const float4* __restrict__ y4) {
  float g0 = 0.f, g1 = 0.f, g2 = 0.f, g3 = 0.f;
#pragma unroll
  for (int c = 0; c < 9; ++c) {
    float4 y = y4[c];
    g0 = fmaf(Gr[c * 4 + 0], y.x, g0);
    g1 = fmaf(Gr[c * 4 + 1], y.y, g1);
    g2 = fmaf(Gr[c * 4 + 2], y.z, g2);
    g3 = fmaf(Gr[c * 4 + 3], y.w, g3);
  }
  return (g0 + g1) + (g2 + g3);
}

__device__ __forceinline__ float wave_sum(float x) {
#pragma unroll
  for (int off = 32; off; off >>= 1) x += __shfl_xor(x, off);
  return x;
}

// A-col a in [0,33): U(a) = a<32 ? a : 36. c columns = u-cols 32..35.
// M stores 8x8 blocks for block-pairs (bi<=bj): mirror via (Ui>>3) vs (Uk>>3).
__global__ __launch_bounds__(256) void solve_kernel(const float* __restrict__ Mw,
                                                    float* __restrict__ out) {
  __shared__ float4 Yb4[2][4][9];  // double-buffered broadcast vector per column
  const int tid  = threadIdx.x;
  const int lane = tid & 63;
  const int col  = tid >> 6;       // one wave per output column
  const bool act = lane < 33;
  const int i  = act ? lane : 0;
  const int Ui = (i < 32) ? i : 36;

  float Gr[36];
#pragma unroll
  for (int k = 0; k < 33; ++k) {
    const int Uk = (k < 32) ? k : 36;
    Gr[k] = ((Ui >> 3) <= (Uk >> 3)) ? Mw[Ui * 40 + Uk] : Mw[Uk * 40 + Ui];
  }
  Gr[33] = Gr[34] = Gr[35] = 0.f;
  const float ci = Mw[Ui * 40 + 32 + col];

  // init broadcast buffers: zeros + initial power vector in buf 0
  if (lane < 9) {
    Yb4[0][col][lane] = make_float4(0.f, 0.f, 0.f, 0.f);
    Yb4[1][col][lane] = make_float4(0.f, 0.f, 0.f, 0.f);
  }
  __syncthreads();
  float v = rsqrtf(33.f);
  if (act) ((float*)&Yb4[0][col][0])[i] = v;
  __syncthreads();

  // power iteration for L = lambda_max(G) (step value only affects rate, not the QP solution)
  for (int it = 0; it < PITERS; ++it) {
    const int rb = it & 1;
    float w = dot36(Gr, &Yb4[rb][col][0]);
    float x = wave_sum(act ? w * w : 0.f);
    float vn = w * rsqrtf(x);
    if (act) ((float*)&Yb4[rb ^ 1][col][0])[i] = vn;
    v = vn;
    __syncthreads();
  }
  {
    const int rb = PITERS & 1;
    float w = dot36(Gr, &Yb4[rb][col][0]);
    v = wave_sum(act ? v * w : 0.f);  // v <- v^T G v (all lanes)
  }
  const float step = 1.f / v;

  // reset Y = 0 for FISTA
  __syncthreads();
  if (act) ((float*)&Yb4[0][col][0])[i] = 0.f;
  __syncthreads();

  float Z = 0.f, Yv = 0.f, t = 1.f;
  for (int it = 0; it < QPITERS; ++it) {
    const int rb = it & 1;
    float g = dot36(Gr, &Yb4[rb][col][0]);
    float zn = Yv - step * (g - ci);
    if (lane < 32) zn = fmaxf(zn, 0.f);  // W rows clamped; bias row free
    float tn = 0.5f * (1.f + sqrtf(fmaf(4.f * t, t, 1.f)));
    float beta = (t - 1.f) / tn;
    float yn = fmaf(beta, zn - Z, zn);
    if (act) ((float*)&Yb4[rb ^ 1][col][0])[i] = yn;
    Z = zn; Yv = yn; t = tn;
    __syncthreads();
  }
  if (lane < 32) out[lane * 4 + col] = Z;  // W is [32,4] row-major
}

extern "C" void kernel_launch(void* const* d_in, const int* in_sizes, int n_in,
                              void* d_out, int out_size, void* d_ws, size_t ws_size,
                              hipStream_t stream) {
  const float* X  = (const float*)d_in[0];
  const float* Yg = (const float*)d_in[1];
  float* Mw  = (float*)d_ws;
  float* out = (float*)d_out;

  hipLaunchKernelGGL(zero_kernel, dim3(7), dim3(256), 0, stream, Mw);
  hipLaunchKernelGGL(gram_kernel, dim3(GRAM_BLOCKS), dim3(256), 0, stream, X, Yg, Mw);
  hipLaunchKernelGGL(solve_kernel, dim3(1), dim3(256), 0, stream, Mw, out);
}

// Round 3
// 406.120 us; speedup vs baseline: 1.4388x; 1.3368x over previous
//
#include <hip/hip_runtime.h>

// NNLS via normal equations + FISTA.
// Phase 1: M = U^T U, U = [X | y | 1] (2e6 x 37, padded to 40). 8x8 per-lane
//          patches, 4 teams/wave, software prefetch, DEFAULT launch bounds
//          (round 2's (256,4) forced acc[8][8] to spill -> 190MB scratch traffic).
// Phase 1b: atomic-free reduction of per-block partials into the 40x40 Gram.
// Phase 2: power iteration (10) + FISTA (64); LDS-broadcast matvec, one wave
//          per output column.

#define NROWS 2000000
#define TR 64                 // tile rows
#define NT (NROWS / TR)       // 31250 tiles, exact
#define US 44                 // LDS row stride (16B-aligned rows)
#define GB 512                // gram blocks (>=2 resident/CU)
#define PITERS 10
#define QPITERS 64

// u-row layout: [x0..x31 | y0..y3 | 1 | 0 0 0] = cols 0..39
__global__ __launch_bounds__(256) void gram_kernel(const float* __restrict__ X,
                                                   const float* __restrict__ Yg,
                                                   float* __restrict__ Pw) {
  __shared__ float sm[3840];  // union: tile 64*44=2816 / reduction 4*960=3840
  const int tid  = threadIdx.x;
  const int lane = tid & 63;
  const int wv   = tid >> 6;
  const int team = lane >> 4;   // 4 teams of 16 lanes
  const int p    = lane & 15;   // patch id; 15 active

  // patch p -> (PI,PJ) in upper triangle of the 5x5 grid of 8x8 col-blocks
  int pp = (p < 15) ? p : 0;
  int PI = 0, rem = pp;
  while (rem >= 5 - PI) { rem -= 5 - PI; ++PI; }
  const int PJ = PI + rem;
  const int ca = PI * 8, cb = PJ * 8;

  const int r0 = tid >> 3;   // staging: row (and row+32)
  const int ch = tid & 7;    // float4 chunk within 32-float x row
  const float4* X4 = (const float4*)X;
  const float4* Y4 = (const float4*)Yg;

  float acc[8][8];
#pragma unroll
  for (int a = 0; a < 8; ++a)
#pragma unroll
    for (int b = 0; b < 8; ++b) acc[a][b] = 0.f;

  int tile = blockIdx.x;
  float4 v0, v1, yv;
  {
    const int gr = tile * TR;
    v0 = X4[(size_t)(gr + r0) * 8 + ch];
    v1 = X4[(size_t)(gr + r0 + 32) * 8 + ch];
    yv = (tid < TR) ? Y4[gr + tid] : make_float4(0.f, 0.f, 0.f, 0.f);
  }

  const int rbase = wv * 16 + team;

  while (tile < NT) {
    __syncthreads();  // previous compute done -> LDS reusable
    *(float4*)&sm[r0 * US + ch * 4]        = v0;
    *(float4*)&sm[(r0 + 32) * US + ch * 4] = v1;
    if (tid < TR) {
      *(float4*)&sm[tid * US + 32] = yv;
      *(float4*)&sm[tid * US + 36] = make_float4(1.f, 0.f, 0.f, 0.f);
    }
    __syncthreads();

    // prefetch next tile; latency hides under this tile's compute
    const int nt = tile + GB;
    if (nt < NT) {
      const int gr = nt * TR;
      v0 = X4[(size_t)(gr + r0) * 8 + ch];
      v1 = X4[(size_t)(gr + r0 + 32) * 8 + ch];
      if (tid < TR) yv = Y4[gr + tid];
    }

#pragma unroll
    for (int rs = 0; rs < 4; ++rs) {
      const float* rowp = &sm[(rbase + rs * 4) * US];
      float4 a0 = *(const float4*)&rowp[ca];
      float4 a1 = *(const float4*)&rowp[ca + 4];
      float4 b0 = *(const float4*)&rowp[cb];
      float4 b1 = *(const float4*)&rowp[cb + 4];
      float av[8] = {a0.x, a0.y, a0.z, a0.w, a1.x, a1.y, a1.z, a1.w};
      float bv[8] = {b0.x, b0.y, b0.z, b0.w, b1.x, b1.y, b1.z, b1.w};
#pragma unroll
      for (int a = 0; a < 8; ++a)
#pragma unroll
        for (int b = 0; b < 8; ++b) acc[a][b] = fmaf(av[a], bv[b], acc[a][b]);
    }
    tile = nt;
  }

  // cross-team reduce (lane bits 4,5), then per-block partial store (no atomics)
#pragma unroll
  for (int a = 0; a < 8; ++a)
#pragma unroll
    for (int b = 0; b < 8; ++b) {
      float v = acc[a][b];
      v += __shfl_xor(v, 16);
      v += __shfl_xor(v, 32);
      acc[a][b] = v;
    }
  __syncthreads();
  if (p < 15 && team == 0) {
#pragma unroll
    for (int a = 0; a < 8; ++a)
#pragma unroll
      for (int b = 0; b < 8; ++b)
        sm[wv * 960 + p * 64 + a * 8 + b] = acc[a][b];
  }
  __syncthreads();
  float* myP = Pw + (size_t)blockIdx.x * 960;
  for (int e = tid; e < 960; e += 256)
    myP[e] = sm[e] + sm[e + 960] + sm[e + 1920] + sm[e + 2880];
}

// Fold GB partials per entry; scatter into the 40x40 Gram (upper 8x8 blocks).
__global__ __launch_bounds__(256) void reduce_kernel(const float* __restrict__ Pw,
                                                     float* __restrict__ Mw) {
  const int t = blockIdx.x * 256 + threadIdx.x;
  if (t >= 960) return;
  float s = 0.f;
  for (int b = 0; b < GB; ++b) s += Pw[(size_t)b * 960 + t];
  int pe = t >> 6, idx = t & 63;
  int bi = 0, r2 = pe;
  while (r2 >= 5 - bi) { r2 -= 5 - bi; ++bi; }
  const int bj = bi + r2;
  Mw[(bi * 8 + (idx >> 3)) * 40 + (bj * 8 + (idx & 7))] = s;
}

// dot of 36-float register row with 36-float LDS vector (uniform addr = broadcast)
__device__ __forceinline__ float dot36(const float* __restrict__ Gr, const float4* __restrict__ y4) {
  float g0 = 0.f, g1 = 0.f, g2 = 0.f, g3 = 0.f;
#pragma unroll
  for (int c = 0; c < 9; ++c) {
    float4 y = y4[c];
    g0 = fmaf(Gr[c * 4 + 0], y.x, g0);
    g1 = fmaf(Gr[c * 4 + 1], y.y, g1);
    g2 = fmaf(Gr[c * 4 + 2], y.z, g2);
    g3 = fmaf(Gr[c * 4 + 3], y.w, g3);
  }
  return (g0 + g1) + (g2 + g3);
}

__device__ __forceinline__ float wave_sum(float x) {
#pragma unroll
  for (int off = 32; off; off >>= 1) x += __shfl_xor(x, off);
  return x;
}

// A-col a in [0,33): U(a) = a<32 ? a : 36. c columns = u-cols 32..35.
// M holds upper 8x8 blocks only: mirror via (Ui>>3) vs (Uk>>3).
__global__ __launch_bounds__(256) void solve_kernel(const float* __restrict__ Mw,
                                                    float* __restrict__ out) {
  __shared__ float4 Yb4[2][4][9];
  const int tid  = threadIdx.x;
  const int lane = tid & 63;
  const int col  = tid >> 6;       // one wave per output column
  const bool act = lane < 33;
  const int i  = act ? lane : 0;
  const int Ui = (i < 32) ? i : 36;

  float Gr[36];
#pragma unroll
  for (int k = 0; k < 33; ++k) {
    const int Uk = (k < 32) ? k : 36;
    Gr[k] = ((Ui >> 3) <= (Uk >> 3)) ? Mw[Ui * 40 + Uk] : Mw[Uk * 40 + Ui];
  }
  Gr[33] = Gr[34] = Gr[35] = 0.f;
  const float ci = Mw[Ui * 40 + 32 + col];

  if (lane < 9) {
    Yb4[0][col][lane] = make_float4(0.f, 0.f, 0.f, 0.f);
    Yb4[1][col][lane] = make_float4(0.f, 0.f, 0.f, 0.f);
  }
  __syncthreads();
  float v = rsqrtf(33.f);
  if (act) ((float*)&Yb4[0][col][0])[i] = v;
  __syncthreads();

  // power iteration for step; any positive-definite Rayleigh quotient in
  // [lambda_min, lambda_max] keeps FISTA stable here (kappa ~ 1.016)
  for (int it = 0; it < PITERS; ++it) {
    const int rb = it & 1;
    float w = dot36(Gr, &Yb4[rb][col][0]);
    float x = wave_sum(act ? w * w : 0.f);
    float vn = w * rsqrtf(x);
    if (act) ((float*)&Yb4[rb ^ 1][col][0])[i] = vn;
    v = vn;
    __syncthreads();
  }
  {
    const int rb = PITERS & 1;
    float w = dot36(Gr, &Yb4[rb][col][0]);
    v = wave_sum(act ? v * w : 0.f);  // v^T G v
  }
  const float step = 1.f / v;

  __syncthreads();
  if (act) ((float*)&Yb4[0][col][0])[i] = 0.f;
  __syncthreads();

  float Z = 0.f, Yv = 0.f, t = 1.f;
  for (int it = 0; it < QPITERS; ++it) {
    const int rb = it & 1;
    float g = dot36(Gr, &Yb4[rb][col][0]);
    float zn = Yv - step * (g - ci);
    if (lane < 32) zn = fmaxf(zn, 0.f);  // W rows clamped; bias row free
    float tn = 0.5f * (1.f + sqrtf(fmaf(4.f * t, t, 1.f)));
    float beta = (t - 1.f) / tn;
    float yn = fmaf(beta, zn - Z, zn);
    if (act) ((float*)&Yb4[rb ^ 1][col][0])[i] = yn;
    Z = zn; Yv = yn; t = tn;
    __syncthreads();
  }
  if (lane < 32) out[lane * 4 + col] = Z;  // W is [32,4] row-major
}

extern "C" void kernel_launch(void* const* d_in, const int* in_sizes, int n_in,
                              void* d_out, int out_size, void* d_ws, size_t ws_size,
                              hipStream_t stream) {
  const float* X  = (const float*)d_in[0];
  const float* Yg = (const float*)d_in[1];
  float* Pw  = (float*)d_ws;                 // GB*960 floats of partials
  float* Mw  = Pw + (size_t)GB * 960;        // 40x40 Gram (upper blocks)
  float* out = (float*)d_out;

  hipLaunchKernelGGL(gram_kernel,   dim3(GB), dim3(256), 0, stream, X, Yg, Pw);
  hipLaunchKernelGGL(reduce_kernel, dim3(4),  dim3(256), 0, stream, Pw, Mw);
  hipLaunchKernelGGL(solve_kernel,  dim3(1),  dim3(256), 0, stream, Mw, out);
}

// Round 4
// 393.012 us; speedup vs baseline: 1.4868x; 1.0334x over previous
//
#include <hip/hip_runtime.h>

// NNLS via normal equations + FISTA.
// Phase 1: M = U^T U, U = [X | y | 1] (2e6 x 37, padded to 40). 8x8 per-lane
//          patches, 4 teams/wave, software prefetch. DEFAULT launch bounds
//          ((256,4) forced acc[8][8] to spill in round 2). Grid 1024 = 4
//          blocks/CU co-resident at ~110 VGPRs.
// Phase 1b: atomic-free coalesced reduction of per-block partials (transposed
//           layout) into the 40x40 Gram, one block per entry.
// Phase 2: power iteration (8) + FISTA (32); LDS-broadcast matvec, one wave
//          per output column. kappa(G)~1.016 -> fp32-converged well before 32.

#define NROWS 2000000
#define TR 64                 // tile rows
#define NT (NROWS / TR)       // 31250 tiles, exact
#define US 44                 // LDS row stride (16B-aligned rows)
#define GB 1024               // gram blocks (4 blocks/CU)
#define PITERS 8
#define QPITERS 32

// u-row layout: [x0..x31 | y0..y3 | 1 | 0 0 0] = cols 0..39
__global__ __launch_bounds__(256) void gram_kernel(const float* __restrict__ X,
                                                   const float* __restrict__ Yg,
                                                   float* __restrict__ Pw) {
  __shared__ float sm[3840];  // union: tile 64*44=2816 / reduction 4*960=3840
  const int tid  = threadIdx.x;
  const int lane = tid & 63;
  const int wv   = tid >> 6;
  const int team = lane >> 4;   // 4 teams of 16 lanes
  const int p    = lane & 15;   // patch id; 15 active

  // patch p -> (PI,PJ) in upper triangle of the 5x5 grid of 8x8 col-blocks
  int pp = (p < 15) ? p : 0;
  int PI = 0, rem = pp;
  while (rem >= 5 - PI) { rem -= 5 - PI; ++PI; }
  const int PJ = PI + rem;
  const int ca = PI * 8, cb = PJ * 8;

  const int r0 = tid >> 3;   // staging: row (and row+32)
  const int ch = tid & 7;    // float4 chunk within 32-float x row
  const float4* X4 = (const float4*)X;
  const float4* Y4 = (const float4*)Yg;

  float acc[8][8];
#pragma unroll
  for (int a = 0; a < 8; ++a)
#pragma unroll
    for (int b = 0; b < 8; ++b) acc[a][b] = 0.f;

  int tile = blockIdx.x;
  float4 v0, v1, yv;
  {
    const int gr = tile * TR;
    v0 = X4[(size_t)(gr + r0) * 8 + ch];
    v1 = X4[(size_t)(gr + r0 + 32) * 8 + ch];
    yv = (tid < TR) ? Y4[gr + tid] : make_float4(0.f, 0.f, 0.f, 0.f);
  }

  const int rbase = wv * 16 + team;

  while (tile < NT) {
    __syncthreads();  // previous compute done -> LDS reusable
    *(float4*)&sm[r0 * US + ch * 4]        = v0;
    *(float4*)&sm[(r0 + 32) * US + ch * 4] = v1;
    if (tid < TR) {
      *(float4*)&sm[tid * US + 32] = yv;
      *(float4*)&sm[tid * US + 36] = make_float4(1.f, 0.f, 0.f, 0.f);
    }
    __syncthreads();

    // prefetch next tile; latency hides under this tile's compute
    const int nt = tile + GB;
    if (nt < NT) {
      const int gr = nt * TR;
      v0 = X4[(size_t)(gr + r0) * 8 + ch];
      v1 = X4[(size_t)(gr + r0 + 32) * 8 + ch];
      if (tid < TR) yv = Y4[gr + tid];
    }

#pragma unroll
    for (int rs = 0; rs < 4; ++rs) {
      const float* rowp = &sm[(rbase + rs * 4) * US];
      float4 a0 = *(const float4*)&rowp[ca];
      float4 a1 = *(const float4*)&rowp[ca + 4];
      float4 b0 = *(const float4*)&rowp[cb];
      float4 b1 = *(const float4*)&rowp[cb + 4];
      float av[8] = {a0.x, a0.y, a0.z, a0.w, a1.x, a1.y, a1.z, a1.w};
      float bv[8] = {b0.x, b0.y, b0.z, b0.w, b1.x, b1.y, b1.z, b1.w};
#pragma unroll
      for (int a = 0; a < 8; ++a)
#pragma unroll
        for (int b = 0; b < 8; ++b) acc[a][b] = fmaf(av[a], bv[b], acc[a][b]);
    }
    tile = nt;
  }

  // cross-team reduce (lane bits 4,5), then transposed partial store:
  // Pw[e*GB + block] -> reduce_kernel reads coalesced
#pragma unroll
  for (int a = 0; a < 8; ++a)
#pragma unroll
    for (int b = 0; b < 8; ++b) {
      float v = acc[a][b];
      v += __shfl_xor(v, 16);
      v += __shfl_xor(v, 32);
      acc[a][b] = v;
    }
  __syncthreads();
  if (p < 15 && team == 0) {
#pragma unroll
    for (int a = 0; a < 8; ++a)
#pragma unroll
      for (int b = 0; b < 8; ++b)
        sm[wv * 960 + p * 64 + a * 8 + b] = acc[a][b];
  }
  __syncthreads();
  for (int e = tid; e < 960; e += 256)
    Pw[(size_t)e * GB + blockIdx.x] = sm[e] + sm[e + 960] + sm[e + 1920] + sm[e + 2880];
}

// One block per Gram entry; coalesced fold of GB partials; scatter into 40x40.
__global__ __launch_bounds__(256) void reduce_kernel(const float* __restrict__ Pw,
                                                     float* __restrict__ Mw) {
  __shared__ float red[4];
  const int t   = blockIdx.x;       // entry 0..959
  const int tid = threadIdx.x;
  float s = 0.f;
#pragma unroll
  for (int k = 0; k < GB / 256; ++k) s += Pw[(size_t)t * GB + k * 256 + tid];
#pragma unroll
  for (int off = 32; off; off >>= 1) s += __shfl_xor(s, off);
  if ((tid & 63) == 0) red[tid >> 6] = s;
  __syncthreads();
  if (tid == 0) {
    float sum = red[0] + red[1] + red[2] + red[3];
    int pe = t >> 6, idx = t & 63;
    int bi = 0, r2 = pe;
    while (r2 >= 5 - bi) { r2 -= 5 - bi; ++bi; }
    const int bj = bi + r2;
    Mw[(bi * 8 + (idx >> 3)) * 40 + (bj * 8 + (idx & 7))] = sum;
  }
}

// dot of 36-float register row with 36-float LDS vector (uniform addr = broadcast)
__device__ __forceinline__ float dot36(const float* __restrict__ Gr, const float4* __restrict__ y4) {
  float g0 = 0.f, g1 = 0.f, g2 = 0.f, g3 = 0.f;
#pragma unroll
  for (int c = 0; c < 9; ++c) {
    float4 y = y4[c];
    g0 = fmaf(Gr[c * 4 + 0], y.x, g0);
    g1 = fmaf(Gr[c * 4 + 1], y.y, g1);
    g2 = fmaf(Gr[c * 4 + 2], y.z, g2);
    g3 = fmaf(Gr[c * 4 + 3], y.w, g3);
  }
  return (g0 + g1) + (g2 + g3);
}

__device__ __forceinline__ float wave_sum(float x) {
#pragma unroll
  for (int off = 32; off; off >>= 1) x += __shfl_xor(x, off);
  return x;
}

// A-col a in [0,33): U(a) = a<32 ? a : 36. c columns = u-cols 32..35.
// M holds upper 8x8 blocks only: mirror via (Ui>>3) vs (Uk>>3).
__global__ __launch_bounds__(256) void solve_kernel(const float* __restrict__ Mw,
                                                    float* __restrict__ out) {
  __shared__ float4 Yb4[2][4][9];
  const int tid  = threadIdx.x;
  const int lane = tid & 63;
  const int col  = tid >> 6;       // one wave per output column
  const bool act = lane < 33;
  const int i  = act ? lane : 0;
  const int Ui = (i < 32) ? i : 36;

  float Gr[36];
#pragma unroll
  for (int k = 0; k < 33; ++k) {
    const int Uk = (k < 32) ? k : 36;
    Gr[k] = ((Ui >> 3) <= (Uk >> 3)) ? Mw[Ui * 40 + Uk] : Mw[Uk * 40 + Ui];
  }
  Gr[33] = Gr[34] = Gr[35] = 0.f;
  const float ci = Mw[Ui * 40 + 32 + col];

  if (lane < 9) {
    Yb4[0][col][lane] = make_float4(0.f, 0.f, 0.f, 0.f);
    Yb4[1][col][lane] = make_float4(0.f, 0.f, 0.f, 0.f);
  }
  __syncthreads();
  float v = rsqrtf(33.f);
  if (act) ((float*)&Yb4[0][col][0])[i] = v;
  __syncthreads();

  // power iteration for step; Rayleigh quotient <= lambda_max, so step >= 1/L;
  // any step in (0, 2/L) converges to the same QP fixed point (kappa ~ 1.016)
  for (int it = 0; it < PITERS; ++it) {
    const int rb = it & 1;
    float w = dot36(Gr, &Yb4[rb][col][0]);
    float x = wave_sum(act ? w * w : 0.f);
    float vn = w * rsqrtf(x);
    if (act) ((float*)&Yb4[rb ^ 1][col][0])[i] = vn;
    v = vn;
    __syncthreads();
  }
  {
    const int rb = PITERS & 1;
    float w = dot36(Gr, &Yb4[rb][col][0]);
    v = wave_sum(act ? v * w : 0.f);  // v^T G v
  }
  const float step = 1.f / v;

  __syncthreads();
  if (act) ((float*)&Yb4[0][col][0])[i] = 0.f;
  __syncthreads();

  float Z = 0.f, Yv = 0.f, t = 1.f;
  for (int it = 0; it < QPITERS; ++it) {
    const int rb = it & 1;
    float g = dot36(Gr, &Yb4[rb][col][0]);
    float zn = Yv - step * (g - ci);
    if (lane < 32) zn = fmaxf(zn, 0.f);  // W rows clamped; bias row free
    float tn = 0.5f * (1.f + sqrtf(fmaf(4.f * t, t, 1.f)));
    float beta = (t - 1.f) / tn;
    float yn = fmaf(beta, zn - Z, zn);
    if (act) ((float*)&Yb4[rb ^ 1][col][0])[i] = yn;
    Z = zn; Yv = yn; t = tn;
    __syncthreads();
  }
  if (lane < 32) out[lane * 4 + col] = Z;  // W is [32,4] row-major
}

extern "C" void kernel_launch(void* const* d_in, const int* in_sizes, int n_in,
                              void* d_out, int out_size, void* d_ws, size_t ws_size,
                              hipStream_t stream) {
  const float* X  = (const float*)d_in[0];
  const float* Yg = (const float*)d_in[1];
  float* Pw  = (float*)d_ws;                 // 960*GB floats of partials (transposed)
  float* Mw  = Pw + (size_t)960 * GB;        // 40x40 Gram (upper blocks)
  float* out = (float*)d_out;

  hipLaunchKernelGGL(gram_kernel,   dim3(GB),  dim3(256), 0, stream, X, Yg, Pw);
  hipLaunchKernelGGL(reduce_kernel, dim3(960), dim3(256), 0, stream, Pw, Mw);
  hipLaunchKernelGGL(solve_kernel,  dim3(1),   dim3(256), 0, stream, Mw, out);
}